// Round 1
// baseline (257.129 us; speedup 1.0000x reference)
//
#include <hip/hip_runtime.h>
#include <math.h>

#define NROW 4096
#define NDIM 128
#define KNN 10

// ws layout (floats): [0,4096) r ; [4096,8192) knn_d ; [8192] scale = -1/(2*sigma)

// ---------------- Kernel 1: gate, masked = x*gate, r = rowsum(masked^2) ------
__global__ __launch_bounds__(128) void k_mask(const float* __restrict__ x,
                                              const float* __restrict__ alpha,
                                              const float* __restrict__ noise,
                                              float* __restrict__ masked,
                                              float* __restrict__ r) {
    int row = blockIdx.x;
    int c = threadIdx.x;
    float g = alpha[c] + 0.5f * noise[c] + 0.5f;
    g = fminf(fmaxf(g, 0.0f), 1.0f);
    float m = x[row * NDIM + c] * g;
    masked[row * NDIM + c] = m;
    float v = m * m;
#pragma unroll
    for (int o = 32; o > 0; o >>= 1) v += __shfl_down(v, o, 64);
    __shared__ float partial[2];
    if ((c & 63) == 0) partial[c >> 6] = v;
    __syncthreads();
    if (c == 0) r[row] = partial[0] + partial[1];
}

// ---------------- Kernel 2: Dx = r_i + r_j - 2 * M M^T  (64x64 tiles) --------
__global__ __launch_bounds__(256) void k_dx(const float* __restrict__ M,
                                            const float* __restrict__ r,
                                            float* __restrict__ Dx) {
    // transposed tiles: As[k][row], pad 68 keeps float4 alignment, <=2-way banks
    __shared__ __align__(16) float As[64][68];
    __shared__ __align__(16) float Bs[64][68];
    int tid = threadIdx.x;
    int bx = blockIdx.x, by = blockIdx.y;
    const float* Ap = M + (size_t)by * 64 * NDIM;
    const float* Bp = M + (size_t)bx * 64 * NDIM;
    int tx = tid & 15, ty = tid >> 4;

    float acc[4][4];
#pragma unroll
    for (int i = 0; i < 4; ++i)
#pragma unroll
        for (int j = 0; j < 4; ++j) acc[i][j] = 0.0f;

    for (int kk = 0; kk < NDIM; kk += 64) {
        __syncthreads();  // protect previous stage reads
#pragma unroll
        for (int l = 0; l < 4; ++l) {
            int rrow = l * 16 + (tid >> 4);
            int ccol = (tid & 15) * 4;
            float4 a = *(const float4*)(Ap + rrow * NDIM + kk + ccol);
            As[ccol + 0][rrow] = a.x;
            As[ccol + 1][rrow] = a.y;
            As[ccol + 2][rrow] = a.z;
            As[ccol + 3][rrow] = a.w;
            float4 b = *(const float4*)(Bp + rrow * NDIM + kk + ccol);
            Bs[ccol + 0][rrow] = b.x;
            Bs[ccol + 1][rrow] = b.y;
            Bs[ccol + 2][rrow] = b.z;
            Bs[ccol + 3][rrow] = b.w;
        }
        __syncthreads();
#pragma unroll 8
        for (int k = 0; k < 64; ++k) {
            float4 a4 = *(const float4*)&As[k][ty * 4];
            float4 b4 = *(const float4*)&Bs[k][tx * 4];
            float av[4] = {a4.x, a4.y, a4.z, a4.w};
            float bv[4] = {b4.x, b4.y, b4.z, b4.w};
#pragma unroll
            for (int i = 0; i < 4; ++i)
#pragma unroll
                for (int j = 0; j < 4; ++j) acc[i][j] += av[i] * bv[j];
        }
    }

    int gi0 = by * 64 + ty * 4;
    int gj0 = bx * 64 + tx * 4;
    float rj[4] = {r[gj0], r[gj0 + 1], r[gj0 + 2], r[gj0 + 3]};
#pragma unroll
    for (int i = 0; i < 4; ++i) {
        float ri = r[gi0 + i];
        float4 o;
        o.x = ri + rj[0] - 2.0f * acc[i][0];
        o.y = ri + rj[1] - 2.0f * acc[i][1];
        o.z = ri + rj[2] - 2.0f * acc[i][2];
        o.w = ri + rj[3] - 2.0f * acc[i][3];
        *(float4*)(Dx + (size_t)(gi0 + i) * NROW + gj0) = o;
    }
}

// ---------------- Kernel 3: knn_d[row] = 10th smallest of Dx row -------------
__global__ __launch_bounds__(256) void k_knn(const float* __restrict__ Dx,
                                             float* __restrict__ knn) {
    __shared__ float cand[NROW];
    __shared__ float wv[4];
    __shared__ int wi[4];
    int row = blockIdx.x, tid = threadIdx.x;
    const float* drow = Dx + (size_t)row * NROW;
#pragma unroll
    for (int l = 0; l < 4; ++l) {
        float4 v = *(const float4*)(drow + l * 1024 + tid * 4);
        *(float4*)&cand[l * 1024 + tid * 4] = v;
    }
    __syncthreads();
    for (int it = 0; it < KNN; ++it) {
        float bv = INFINITY;
        int bi = 0;
        for (int c = tid; c < NROW; c += 256) {
            float v = cand[c];
            if (v < bv) { bv = v; bi = c; }
        }
#pragma unroll
        for (int o = 32; o > 0; o >>= 1) {
            float ov = __shfl_down(bv, o, 64);
            int oi = __shfl_down(bi, o, 64);
            if (ov < bv) { bv = ov; bi = oi; }
        }
        int lane = tid & 63, wid = tid >> 6;
        if (lane == 0) { wv[wid] = bv; wi[wid] = bi; }
        __syncthreads();
        if (tid == 0) {
            float b = wv[0];
            int bj = wi[0];
            for (int w = 1; w < 4; ++w)
                if (wv[w] < b) { b = wv[w]; bj = wi[w]; }
            cand[bj] = INFINITY;
            if (it == KNN - 1) knn[row] = b;
        }
        __syncthreads();
    }
}

// ---------------- Kernel 4: median of knn -> scale = -1/(2*sigma) ------------
__global__ __launch_bounds__(1024) void k_sigma(const float* __restrict__ knn,
                                                float* __restrict__ scale_out) {
    __shared__ float s[NROW];
    int tid = threadIdx.x;
#pragma unroll
    for (int l = 0; l < 4; ++l) s[tid + l * 1024] = knn[tid + l * 1024];
    __syncthreads();
    for (int k = 2; k <= NROW; k <<= 1) {
        for (int j = k >> 1; j > 0; j >>= 1) {
            for (int t = tid; t < NROW; t += 1024) {
                int l = t ^ j;
                if (l > t) {
                    bool up = ((t & k) == 0);
                    float a = s[t], b = s[l];
                    if ((a > b) == up) { s[t] = b; s[l] = a; }
                }
            }
            __syncthreads();
        }
    }
    if (tid == 0) {
        float sigma = 0.5f * (s[2047] + s[2048]);
        if (sigma < 1e-8f) sigma = 1.0f;
        scale_out[0] = -1.0f / (2.0f * sigma);
    }
}

// ---------------- Kernel 5: P = exp(Dx*scale) / rowsum, in place -------------
__global__ __launch_bounds__(256) void k_norm(float* __restrict__ Dx,
                                              const float* __restrict__ scale_p) {
    int row = blockIdx.x, tid = threadIdx.x;
    float scale = scale_p[0];
    float* drow = Dx + (size_t)row * NROW;
    float4 v[4];
    float sum = 0.0f;
#pragma unroll
    for (int l = 0; l < 4; ++l) {
        v[l] = *(float4*)(drow + l * 1024 + tid * 4);
        v[l].x = __expf(v[l].x * scale);
        v[l].y = __expf(v[l].y * scale);
        v[l].z = __expf(v[l].z * scale);
        v[l].w = __expf(v[l].w * scale);
        sum += v[l].x + v[l].y + v[l].z + v[l].w;
    }
#pragma unroll
    for (int o = 32; o > 0; o >>= 1) sum += __shfl_down(sum, o, 64);
    __shared__ float ps[4];
    int lane = tid & 63, wid = tid >> 6;
    if (lane == 0) ps[wid] = sum;
    __syncthreads();
    float inv = 1.0f / (ps[0] + ps[1] + ps[2] + ps[3]);
#pragma unroll
    for (int l = 0; l < 4; ++l) {
        v[l].x *= inv;
        v[l].y *= inv;
        v[l].z *= inv;
        v[l].w *= inv;
        *(float4*)(drow + l * 1024 + tid * 4) = v[l];
    }
}

extern "C" void kernel_launch(void* const* d_in, const int* in_sizes, int n_in,
                              void* d_out, int out_size, void* d_ws, size_t ws_size,
                              hipStream_t stream) {
    const float* x = (const float*)d_in[0];
    const float* alpha = (const float*)d_in[1];
    const float* noise = (const float*)d_in[2];
    float* out = (float*)d_out;
    float* P = out;                                // N*N, also Dx scratch
    float* masked = out + (size_t)NROW * NROW;     // N*D
    float* ws = (float*)d_ws;
    float* r = ws;            // 4096
    float* knn = ws + NROW;   // 4096
    float* scale = ws + 2 * NROW;  // 1

    k_mask<<<NROW, 128, 0, stream>>>(x, alpha, noise, masked, r);
    k_dx<<<dim3(NROW / 64, NROW / 64), 256, 0, stream>>>(masked, r, P);
    k_knn<<<NROW, 256, 0, stream>>>(P, knn);
    k_sigma<<<1, 1024, 0, stream>>>(knn, scale);
    k_norm<<<NROW, 256, 0, stream>>>(P, scale);
}

// Round 2
// 172.982 us; speedup vs baseline: 1.4864x; 1.4864x over previous
//
#include <hip/hip_runtime.h>
#include <math.h>

#define NROW 4096
#define NDIM 128
#define KNN 10
#define LDSS 136  // bf16 LDS row stride (128 + 8 pad -> 2-way banks, 16B aligned)

typedef __bf16 bf16x8 __attribute__((ext_vector_type(8)));
typedef float f32x4 __attribute__((ext_vector_type(4)));

__device__ inline unsigned short f2bf(float f) {  // RTNE f32->bf16
    unsigned int u = __float_as_uint(f);
    u += 0x7FFFu + ((u >> 16) & 1u);
    return (unsigned short)(u >> 16);
}

// ---------------- Kernel 1: gate, masked = x*gate, r = rowsum(masked^2) ------
__global__ __launch_bounds__(128) void k_mask(const float* __restrict__ x,
                                              const float* __restrict__ alpha,
                                              const float* __restrict__ noise,
                                              float* __restrict__ masked,
                                              float* __restrict__ r) {
    int row = blockIdx.x;
    int c = threadIdx.x;
    float g = alpha[c] + 0.5f * noise[c] + 0.5f;
    g = fminf(fmaxf(g, 0.0f), 1.0f);
    float m = x[row * NDIM + c] * g;
    masked[row * NDIM + c] = m;
    float v = m * m;
#pragma unroll
    for (int o = 32; o > 0; o >>= 1) v += __shfl_down(v, o, 64);
    __shared__ float partial[2];
    if ((c & 63) == 0) partial[c >> 6] = v;
    __syncthreads();
    if (c == 0) r[row] = partial[0] + partial[1];
}

// ---------------- Kernel 2: Dx = r_i + r_j - 2*M M^T via bf16 MFMA -----------
// 128x128 tile/block, 256 thr (4 waves, each a 64x64 quadrant), full K=128 in LDS.
__global__ __launch_bounds__(256) void k_dx(const float* __restrict__ M,
                                            const float* __restrict__ r,
                                            float* __restrict__ Dx) {
    __shared__ __align__(16) __bf16 Asm[128 * LDSS];
    __shared__ __align__(16) __bf16 Bsm[128 * LDSS];
    int tid = threadIdx.x;
    int bx = blockIdx.x, by = blockIdx.y;

    // ---- stage both tiles, f32 -> bf16 on the fly ----
    {
        const float* Ap = M + (size_t)by * 128 * NDIM;
        const float* Bp = M + (size_t)bx * 128 * NDIM;
        int c = (tid & 15) * 8;   // 8 floats per thread per row-chunk
        int r0 = tid >> 4;
#pragma unroll
        for (int i = 0; i < 8; ++i) {
            int row = r0 + i * 16;
            float4 a0 = *(const float4*)(Ap + row * NDIM + c);
            float4 a1 = *(const float4*)(Ap + row * NDIM + c + 4);
            uint4 pa;
            pa.x = (unsigned)f2bf(a0.x) | ((unsigned)f2bf(a0.y) << 16);
            pa.y = (unsigned)f2bf(a0.z) | ((unsigned)f2bf(a0.w) << 16);
            pa.z = (unsigned)f2bf(a1.x) | ((unsigned)f2bf(a1.y) << 16);
            pa.w = (unsigned)f2bf(a1.z) | ((unsigned)f2bf(a1.w) << 16);
            *(uint4*)&Asm[row * LDSS + c] = pa;
            float4 b0 = *(const float4*)(Bp + row * NDIM + c);
            float4 b1 = *(const float4*)(Bp + row * NDIM + c + 4);
            uint4 pb;
            pb.x = (unsigned)f2bf(b0.x) | ((unsigned)f2bf(b0.y) << 16);
            pb.y = (unsigned)f2bf(b0.z) | ((unsigned)f2bf(b0.w) << 16);
            pb.z = (unsigned)f2bf(b1.x) | ((unsigned)f2bf(b1.y) << 16);
            pb.w = (unsigned)f2bf(b1.z) | ((unsigned)f2bf(b1.w) << 16);
            *(uint4*)&Bsm[row * LDSS + c] = pb;
        }
    }
    __syncthreads();

    int wave = tid >> 6, lane = tid & 63;
    int wr = wave >> 1, wc = wave & 1;   // 64x64 quadrant
    int quad = lane >> 4, l15 = lane & 15;

    f32x4 acc[4][4];
#pragma unroll
    for (int i = 0; i < 4; ++i)
#pragma unroll
        for (int j = 0; j < 4; ++j) acc[i][j] = (f32x4)(0.0f);

#pragma unroll
    for (int kk = 0; kk < 128; kk += 32) {
        int ka = kk + quad * 8;
        bf16x8 af[4], bfr[4];
#pragma unroll
        for (int ti = 0; ti < 4; ++ti)
            af[ti] = *(const bf16x8*)&Asm[(wr * 64 + ti * 16 + l15) * LDSS + ka];
#pragma unroll
        for (int tj = 0; tj < 4; ++tj)
            bfr[tj] = *(const bf16x8*)&Bsm[(wc * 64 + tj * 16 + l15) * LDSS + ka];
#pragma unroll
        for (int ti = 0; ti < 4; ++ti)
#pragma unroll
            for (int tj = 0; tj < 4; ++tj)
                acc[ti][tj] = __builtin_amdgcn_mfma_f32_16x16x32_bf16(
                    af[ti], bfr[tj], acc[ti][tj], 0, 0, 0);
    }

    // ---- epilogue: Dx = r_i + r_j - 2*acc ----
    int gi_base = by * 128 + wr * 64;
    int gj_base = bx * 128 + wc * 64;
    float rrow[4][4], rcol[4];
#pragma unroll
    for (int ti = 0; ti < 4; ++ti)
#pragma unroll
        for (int rg = 0; rg < 4; ++rg)
            rrow[ti][rg] = r[gi_base + ti * 16 + quad * 4 + rg];
#pragma unroll
    for (int tj = 0; tj < 4; ++tj) rcol[tj] = r[gj_base + tj * 16 + l15];
#pragma unroll
    for (int ti = 0; ti < 4; ++ti)
#pragma unroll
        for (int rg = 0; rg < 4; ++rg) {
            int grow = gi_base + ti * 16 + quad * 4 + rg;
#pragma unroll
            for (int tj = 0; tj < 4; ++tj) {
                int gcol = gj_base + tj * 16 + l15;
                Dx[(size_t)grow * NROW + gcol] =
                    rrow[ti][rg] + rcol[tj] - 2.0f * acc[ti][tj][rg];
            }
        }
}

// ---------------- Kernel 3: knn_d[row] = 10th smallest of Dx row -------------
__global__ __launch_bounds__(256) void k_knn(const float* __restrict__ Dx,
                                             float* __restrict__ knn) {
    __shared__ float cand[NROW];
    __shared__ float wv[4];
    __shared__ int wi[4];
    int row = blockIdx.x, tid = threadIdx.x;
    const float* drow = Dx + (size_t)row * NROW;
#pragma unroll
    for (int l = 0; l < 4; ++l) {
        float4 v = *(const float4*)(drow + l * 1024 + tid * 4);
        *(float4*)&cand[l * 1024 + tid * 4] = v;
    }
    __syncthreads();
    for (int it = 0; it < KNN; ++it) {
        float bv = INFINITY;
        int bi = 0;
        for (int c = tid; c < NROW; c += 256) {
            float v = cand[c];
            if (v < bv) { bv = v; bi = c; }
        }
#pragma unroll
        for (int o = 32; o > 0; o >>= 1) {
            float ov = __shfl_down(bv, o, 64);
            int oi = __shfl_down(bi, o, 64);
            if (ov < bv) { bv = ov; bi = oi; }
        }
        int lane = tid & 63, wid = tid >> 6;
        if (lane == 0) { wv[wid] = bv; wi[wid] = bi; }
        __syncthreads();
        if (tid == 0) {
            float b = wv[0];
            int bj = wi[0];
            for (int w = 1; w < 4; ++w)
                if (wv[w] < b) { b = wv[w]; bj = wi[w]; }
            cand[bj] = INFINITY;
            if (it == KNN - 1) knn[row] = b;
        }
        __syncthreads();
    }
}

// ---------------- Kernel 4: median via 3-round radix select ------------------
__device__ inline unsigned fmap(float f) {
    unsigned b = __float_as_uint(f);
    return b ^ ((b >> 31) ? 0xFFFFFFFFu : 0x80000000u);
}
__device__ inline float funmap(unsigned u) {
    unsigned b = (u & 0x80000000u) ? (u ^ 0x80000000u) : ~u;
    return __uint_as_float(b);
}

__global__ __launch_bounds__(1024) void k_sigma(const float* __restrict__ knn,
                                                float* __restrict__ scale_out) {
    __shared__ unsigned keys[NROW];
    __shared__ unsigned hist[2048];
    __shared__ unsigned s_prefix, s_R;
    __shared__ float red_f[16];
    __shared__ unsigned red_u[16];
    int tid = threadIdx.x;
    if (tid == 0) { s_prefix = 0; s_R = 2047; }
#pragma unroll
    for (int l = 0; l < 4; ++l) keys[tid + l * 1024] = fmap(knn[tid + l * 1024]);
    __syncthreads();

    const int shifts[3] = {21, 10, 0};
    const int widths[3] = {11, 11, 10};
    for (int rd = 0; rd < 3; ++rd) {
        int sh = shifts[rd], w = widths[rd];
        unsigned nb = 1u << w;
        hist[tid] = 0;
        hist[tid + 1024] = 0;
        __syncthreads();
        unsigned prefix = s_prefix;
        unsigned R = s_R;
        int hsh = sh + w;
#pragma unroll
        for (int l = 0; l < 4; ++l) {
            unsigned k = keys[tid + l * 1024];
            bool match = (rd == 0) || ((k >> hsh) == prefix);
            if (match) atomicAdd(&hist[(k >> sh) & (nb - 1u)], 1u);
        }
        __syncthreads();
        if (tid < 64) {
            unsigned chunk = nb >> 6;
            unsigned base = tid * chunk;
            unsigned lsum = 0;
            for (unsigned i = 0; i < chunk; ++i) lsum += hist[base + i];
            unsigned pfx = lsum;
#pragma unroll
            for (int o = 1; o < 64; o <<= 1) {
                unsigned v = __shfl_up(pfx, o, 64);
                if (tid >= o) pfx += v;
            }
            unsigned excl = pfx - lsum;
            if (R >= excl && R < excl + lsum) {
                unsigned cum = excl;
                for (unsigned i = 0; i < chunk; ++i) {
                    unsigned h = hist[base + i];
                    if (R < cum + h) {
                        s_prefix = (prefix << w) | (base + i);
                        s_R = R - cum;
                        break;
                    }
                    cum += h;
                }
            }
        }
        __syncthreads();
    }

    unsigned mlk = s_prefix;  // full 32-bit key of rank-2047 value
    // count <= mlk, min key > mlk
    unsigned cnt = 0, mng = 0xFFFFFFFFu;
#pragma unroll
    for (int l = 0; l < 4; ++l) {
        unsigned k = keys[tid + l * 1024];
        if (k <= mlk) cnt++;
        else mng = min(mng, k);
    }
#pragma unroll
    for (int o = 32; o > 0; o >>= 1) {
        cnt += __shfl_down(cnt, o, 64);
        mng = min(mng, (unsigned)__shfl_down(mng, o, 64));
    }
    int lane = tid & 63, wid = tid >> 6;
    if (lane == 0) { red_u[wid] = cnt; red_f[wid] = __uint_as_float(mng); }
    __syncthreads();
    if (tid == 0) {
        unsigned ctot = 0, m = 0xFFFFFFFFu;
        for (int w = 0; w < 16; ++w) {
            ctot += red_u[w];
            m = min(m, __float_as_uint(red_f[w]));
        }
        float ml = funmap(mlk);
        float mu = (ctot >= 2049u) ? ml : funmap(m);
        float sigma = 0.5f * (mu + ml);
        if (sigma < 1e-8f) sigma = 1.0f;
        scale_out[0] = -1.0f / (2.0f * sigma);
    }
}

// ---------------- Kernel 5: P = exp(Dx*scale) / rowsum, in place -------------
__global__ __launch_bounds__(256) void k_norm(float* __restrict__ Dx,
                                              const float* __restrict__ scale_p) {
    int row = blockIdx.x, tid = threadIdx.x;
    float scale = scale_p[0];
    float* drow = Dx + (size_t)row * NROW;
    float4 v[4];
    float sum = 0.0f;
#pragma unroll
    for (int l = 0; l < 4; ++l) {
        v[l] = *(float4*)(drow + l * 1024 + tid * 4);
        v[l].x = __expf(v[l].x * scale);
        v[l].y = __expf(v[l].y * scale);
        v[l].z = __expf(v[l].z * scale);
        v[l].w = __expf(v[l].w * scale);
        sum += v[l].x + v[l].y + v[l].z + v[l].w;
    }
#pragma unroll
    for (int o = 32; o > 0; o >>= 1) sum += __shfl_down(sum, o, 64);
    __shared__ float ps[4];
    int lane = tid & 63, wid = tid >> 6;
    if (lane == 0) ps[wid] = sum;
    __syncthreads();
    float inv = 1.0f / (ps[0] + ps[1] + ps[2] + ps[3]);
#pragma unroll
    for (int l = 0; l < 4; ++l) {
        v[l].x *= inv;
        v[l].y *= inv;
        v[l].z *= inv;
        v[l].w *= inv;
        *(float4*)(drow + l * 1024 + tid * 4) = v[l];
    }
}

extern "C" void kernel_launch(void* const* d_in, const int* in_sizes, int n_in,
                              void* d_out, int out_size, void* d_ws, size_t ws_size,
                              hipStream_t stream) {
    const float* x = (const float*)d_in[0];
    const float* alpha = (const float*)d_in[1];
    const float* noise = (const float*)d_in[2];
    float* out = (float*)d_out;
    float* P = out;                             // N*N, also Dx scratch
    float* masked = out + (size_t)NROW * NROW;  // N*D
    float* ws = (float*)d_ws;
    float* r = ws;                 // 4096
    float* knn = ws + NROW;        // 4096
    float* scale = ws + 2 * NROW;  // 1

    k_mask<<<NROW, 128, 0, stream>>>(x, alpha, noise, masked, r);
    k_dx<<<dim3(NROW / 128, NROW / 128), 256, 0, stream>>>(masked, r, P);
    k_knn<<<NROW, 256, 0, stream>>>(P, knn);
    k_sigma<<<1, 1024, 0, stream>>>(knn, scale);
    k_norm<<<NROW, 256, 0, stream>>>(P, scale);
}